// Round 7
// baseline (339.134 us; speedup 1.0000x reference)
//
#include <hip/hip_runtime.h>

// CRF loss (B=1024, T=512, L=62, K=64) for MI355X / gfx950.
// R7: TWO-WAVE fwd/bwd split. R6 proved the factorization (absmax 0.0) but
// single-wave ILP overlap failed: regalloc serialized the two step_ss calls
// (VGPR 88, +80% VALU work from copies, 196us > R4's 118us). Now each chain
// runs in its OWN WAVE of a 128-thread block -- hardware overlaps waves
// (different SIMDs or wave-interleave), compiler sees only the R4-proven
// single-chain body (one Eh[32], one r[32]). Sequential depth 512 -> ~256.
//   wave0 fwd: qf_j <- Wf_j * sum_i qf_i E[i][j]   (dot vs E columns)
//   wave1 bwd: qb_i <- sum_j E[i][j] (Wb_j qb_j)   (dot vs E rows)
// bwd init analytic: qb = E[:,63] (exp of end-obs = delta on lane 63),
// W row slen-1 folded in. W rows: fwd 0..tm, bwd tm+1..slen-1 (last bwd
// step W=1). Combine at cut: logZ2 = c_base + Ci_f + Ci_b + log2(sum qf*qb)
// via LDS + one __syncthreads (qb=0 on lanes 62/63 kills junk).
// Per-chain step: gather-all DPP/permlane tree (R4-validated probe, both
// swap outputs kept -> 32 h2 regs), 32 fdot2 on 8 accumulators, SAME-STEP
// exponent renorm (exact 2^-(ex+6); R5's delayed renorm = unstable).
// Gold path split 4 chunks/wave, merged in LDS; one atomicAdd per block.

#define SMALLF   (-1000.0f)
#define LOG2E_F  1.4426950408889634f
#define LN2_F    0.6931471805599453f

#if defined(__has_builtin)
#if __has_builtin(__builtin_amdgcn_exp2f)
#define EXP2F(x) __builtin_amdgcn_exp2f(x)
#else
#define EXP2F(x) exp2f(x)
#endif
#if __has_builtin(__builtin_amdgcn_logf)
#define LOG2F(x) __builtin_amdgcn_logf(x)
#else
#define LOG2F(x) log2f(x)
#endif
#else
#define EXP2F(x) exp2f(x)
#define LOG2F(x) log2f(x)
#endif

typedef _Float16 h2 __attribute__((ext_vector_type(2)));

#if defined(__has_builtin) && __has_builtin(__builtin_amdgcn_fdot2)
#define FDOT2(a, b, c) __builtin_amdgcn_fdot2((a), (b), (c), false)
#else
#define FDOT2(a, b, c) fmaf((float)(a).x, (float)(b).x, \
                            fmaf((float)(a).y, (float)(b).y, (c)))
#endif

// DPP move: dst[lane] = src[perm(lane)], full masks, all lanes active.
template <int CTRL>
__device__ __forceinline__ unsigned dppmov(unsigned v) {
    return (unsigned)__builtin_amdgcn_update_dpp((int)v, (int)v, CTRL, 0xF, 0xF, false);
}
#define DPP_QP_X1 0xB1   // quad_perm xor1
#define DPP_QP_X2 0x4E   // quad_perm xor2
#define DPP_ROR4  0x124
#define DPP_ROR8  0x128  // within-16 rotate 8 = xor8 either direction
#define DPP_ROR12 0x12C

// +-4 stage in the 16-row: ror4/ror12 select by lane bit2; probe records
// the exact resulting row order.
__device__ __forceinline__ unsigned x4sel(unsigned v, bool b2) {
    const unsigned a = dppmov<DPP_ROR4>(v);
    const unsigned b = dppmov<DPP_ROR12>(v);
    return b2 ? a : b;
}

// Half-swap exchanges, BOTH outputs kept; probe tracks orientation.
#define SWAP16(a, b) asm("v_permlane16_swap_b32 %0, %1" : "+v"(a), "+v"(b))
#define SWAP32(a, b) asm("v_permlane32_swap_b32 %0, %1" : "+v"(a), "+v"(b))

__device__ __forceinline__ float bcast_first(float v) {
    return __uint_as_float(__builtin_amdgcn_readfirstlane(__float_as_uint(v)));
}

// SAME-STEP wave-uniform scale 2^-(ex+6) from ss_lane0; accumulates into Ci.
__device__ __forceinline__ float step_scale(float ss, int& Ci) {
    const float s0 = bcast_first(ss);
    const int ex = (int)((__float_as_uint(s0) >> 23) & 0xFF) - 127;  // s0>0 normal
    Ci += ex + 6;
    return __uint_as_float((unsigned)(127 - ex - 6) << 23);          // exact 2^-(ex+6)
}

// ss[lane] = sum over ALL 64 slots i of h_i * Eh[probed slot][lane].
// Gather-all tree: pack(me,x1) -> x2 -> x4sel -> x8 -> swap16(both) ->
// swap32(both) = 32 h2 regs; 32 fdot2 on 8 accumulators; 3-level add tree.
__device__ __forceinline__ float step_ss(float hf,
                                         const h2* __restrict__ Eh,
                                         bool b2) {
    unsigned r[32];
    const unsigned n1 = dppmov<DPP_QP_X1>(__float_as_uint(hf));
    r[0] = __builtin_bit_cast(unsigned,
              __builtin_amdgcn_cvt_pkrtz(hf, __uint_as_float(n1)));
    r[1] = dppmov<DPP_QP_X2>(r[0]);
    r[2] = x4sel(r[0], b2);
    r[3] = x4sel(r[1], b2);
    r[4] = dppmov<DPP_ROR8>(r[0]);
    r[5] = dppmov<DPP_ROR8>(r[1]);
    r[6] = dppmov<DPP_ROR8>(r[2]);
    r[7] = dppmov<DPP_ROR8>(r[3]);
#pragma unroll
    for (int k = 0; k < 8; ++k) { r[8 + k] = r[k]; SWAP16(r[k], r[8 + k]); }
#pragma unroll
    for (int k = 0; k < 16; ++k) { r[16 + k] = r[k]; SWAP32(r[k], r[16 + k]); }
    float a[8];
#pragma unroll
    for (int j = 0; j < 8; ++j) a[j] = 0.f;
#pragma unroll
    for (int k = 0; k < 32; ++k)
        a[k & 7] = FDOT2(__builtin_bit_cast(h2, r[k]), Eh[k], a[k & 7]);
    return ((a[0] + a[1]) + (a[2] + a[3])) + ((a[4] + a[5]) + (a[6] + a[7]));
}

__global__ __launch_bounds__(128, 1) void crf_fused_kernel(
    const float* __restrict__ pred,     // (B,T,L)
    const int*   __restrict__ ref,      // (B,T)
    const int*   __restrict__ seq_len,  // (B,)
    const float* __restrict__ trans,    // (64,64)
    float*       __restrict__ out,      // scalar, pre-zeroed
    int T, int L)
{
    const int b    = blockIdx.x;
    const unsigned tid  = threadIdx.x;
    const unsigned lane = tid & 63u;
    const bool w0 = (tid < 64u);            // wave0 = forward chain
    const int slen = seq_len[b];
    const int nmid = slen - 1;
    const float* prow = pred + (size_t)b * T * L;
    const int*   rrow = ref  + (size_t)b * T;
    const bool mine = (lane < 62);
    const bool b2 = (lane & 4u) != 0;

    __shared__ float Af[64], Ab[64];
    __shared__ float gpart[2];
    __shared__ int   Cpart[2];

    // ---- gold score: 4 chunks per wave (w0: t<256, w1: t>=256)
    const int kb = w0 ? 0 : 4;
    int cidx[4], pidx[4];
#pragma unroll
    for (int k = 0; k < 4; ++k) {
        const int t = (int)lane + ((k + kb) << 6);
        cidx[k] = (t < slen) ? rrow[t] : 0;
        pidx[k] = (t >= 1 && t < slen) ? rrow[t - 1] : 0;
    }
    float gacc = 0.f;
#pragma unroll
    for (int k = 0; k < 4; ++k) {
        const int t = (int)lane + ((k + kb) << 6);
        if (t < slen) {
            gacc += prow[(size_t)t * L + cidx[k]];
            if (t >= 1) gacc += trans[(pidx[k] << 6) + cidx[k]];
        }
    }
    if (w0 && lane == 0)
        gacc += trans[(62 << 6) + rrow[0]] + trans[(rrow[slen - 1] << 6) + 63];

    // ---- probe the gather tree (per wave; payload = packed lane ids) -----
    unsigned gp[32];
    gp[0] = lane | (dppmov<DPP_QP_X1>(lane) << 16);
    gp[1] = dppmov<DPP_QP_X2>(gp[0]);
    gp[2] = x4sel(gp[0], b2);
    gp[3] = x4sel(gp[1], b2);
    gp[4] = dppmov<DPP_ROR8>(gp[0]);
    gp[5] = dppmov<DPP_ROR8>(gp[1]);
    gp[6] = dppmov<DPP_ROR8>(gp[2]);
    gp[7] = dppmov<DPP_ROR8>(gp[3]);
#pragma unroll
    for (int k = 0; k < 8; ++k) { gp[8 + k] = gp[k]; SWAP16(gp[k], gp[8 + k]); }
#pragma unroll
    for (int k = 0; k < 16; ++k) { gp[16 + k] = gp[k]; SWAP32(gp[k], gp[16 + k]); }

    // ---- E fragments in probed order: w0 column-dot, w1 row-dot ----------
    h2 Eh[32];
    float psum = 0.f;                        // meaningful for w0 only
#pragma unroll
    for (int k = 0; k < 32; ++k) {
        const unsigned rlo = gp[k] & 0xFFFFu;
        const unsigned rhi = gp[k] >> 16;
        const unsigned iLo = w0 ? (rlo * 64u + lane) : (lane * 64u + rlo);
        const unsigned iHi = w0 ? (rhi * 64u + lane) : (lane * 64u + rhi);
        const float e0 = EXP2F(trans[iLo] * LOG2E_F);
        const float e1 = EXP2F(trans[iHi] * LOG2E_F);
        Eh[k].x = (_Float16)e0; Eh[k].y = (_Float16)e1;
        psum += e0 + e1;                     // rows 62/63 contribute 0 (w0)
    }

    // ---- chain split (R6-verified): fwd rows 0..tm, bwd rows slen-1..tm+1
    const int fwd_mid = nmid >> 1;
    const int bwd_mid = nmid - fwd_mid;
    const int nsteps  = w0 ? fwd_mid : bwd_mid;

    // ---- init
    int Ci = 0;
    const float c_base = SMALLF * LOG2E_F;
    float h;
    if (w0) {                                // row 0 + psum, exact renorm
        const float q0 = psum * EXP2F((mine ? prow[lane] : 0.f) * LOG2E_F);
        const float sc = step_scale(q0, Ci);
        h = q0 * sc;
    } else {                                 // qb = E[:,63]; fold W row slen-1
        const float Elast = EXP2F(trans[lane * 64u + 63u] * LOG2E_F); // 0 on 62/63
        float Wb0 = 1.0f;
        if (bwd_mid > 0) {
            const float pv = mine ? prow[(size_t)(slen - 1) * L + lane] : 0.f;
            Wb0 = mine ? EXP2F(pv * LOG2E_F) : 0.f;
        }
        h = Elast * Wb0;                     // f16-safe range unrenormed
    }

    // ---- middle steps; W row for step m: w0: m+1, w1: slen-2-m (last: W=1)
    float cur[4];
#pragma unroll
    for (int u = 0; u < 4; ++u) {
        int r = w0 ? (u + 1) : (slen - 2 - u);
        r = (r < 0) ? 0 : ((r < T) ? r : (T - 1));
        cur[u] = mine ? prow[(size_t)r * L + lane] : 0.f;
    }

    for (int m0 = 0; m0 < nsteps; m0 += 4) {
        float W[4], nxt[4];
#pragma unroll
        for (int u = 0; u < 4; ++u)          // w0: lanes 62/63 -> exp(0)=1
            W[u] = (w0 || mine) ? EXP2F(cur[u] * LOG2E_F) : 0.f;
#pragma unroll
        for (int u = 0; u < 4; ++u) {        // prefetch next chunk
            int r = w0 ? (m0 + 5 + u) : (slen - 6 - m0 - u);
            r = (r < 0) ? 0 : ((r < T) ? r : (T - 1));
            nxt[u] = mine ? prow[(size_t)r * L + lane] : 0.f;
        }
#pragma unroll
        for (int u = 0; u < 4; ++u) {
            const int m = m0 + u;
            if (m < nsteps) {                // wave-uniform predicate
                const float ss = step_ss(h, Eh, b2);
                const float sc = step_scale(ss, Ci);
                const float Wu = (!w0 && m == nsteps - 1) ? 1.0f : W[u];
                h = ss * (Wu * sc);
            }
        }
#pragma unroll
        for (int u = 0; u < 4; ++u) cur[u] = nxt[u];
    }

    // ---- in-wave gold reduction, publish chain results -------------------
#pragma unroll
    for (int k = 32; k >= 1; k >>= 1)
        gacc += __shfl_xor(gacc, k, 64);

    if (w0) Af[lane] = h; else Ab[lane] = h;
    if (lane == 0) { gpart[w0 ? 0 : 1] = gacc; Cpart[w0 ? 0 : 1] = Ci; }
    __syncthreads();

    // ---- combine at the cut: S = sum_i qf_i*qb_i (qb=0 on lanes 62/63) ---
    if (w0) {
        float p = Af[lane] * Ab[lane];
#pragma unroll
        for (int k = 32; k >= 1; k >>= 1)
            p += __shfl_xor(p, k, 64);
        if (lane == 0) {
            const float logZ2 = c_base + (float)(Cpart[0] + Cpart[1]) + LOG2F(p);
            atomicAdd(out, LN2_F * logZ2 - (gpart[0] + gpart[1]));
        }
    }
}

extern "C" void kernel_launch(void* const* d_in, const int* in_sizes, int n_in,
                              void* d_out, int out_size, void* d_ws, size_t ws_size,
                              hipStream_t stream) {
    const float* pred  = (const float*)d_in[0];
    const int*   ref   = (const int*)  d_in[1];
    const int*   slen  = (const int*)  d_in[2];
    const float* trans = (const float*)d_in[3];

    const int B = in_sizes[2];                 // 1024
    const int T = in_sizes[1] / B;             // 512
    const int L = in_sizes[0] / in_sizes[1];   // 62

    hipMemsetAsync(d_out, 0, sizeof(float), stream);
    crf_fused_kernel<<<B, 128, 0, stream>>>(pred, ref, slen, trans,
                                            (float*)d_out, T, L);
}

// Round 8
// 337.231 us; speedup vs baseline: 1.0056x; 1.0056x over previous
//
#include <hip/hip_runtime.h>

// CRF loss (B=1024, T=512, L=62, K=64) for MI355X / gfx950.
// R8: fwd/bwd chains in SEPARATE single-wave blocks (grid 2048), exact
// R4-proven chain engine per block. R6 (one-wave ILP) and R7 (two waves,
// one block) both landed ~195us -- worse than even full serialization of
// two 256-step chains at R4's 553 cy/step (118us), so the intra-block
// plumbing itself (per-lane w0 selects, chunk-4) bloated the step. Here:
//   block 2b   = forward chain of batch b (rows 0..tm)
//   block 2b+1 = backward chain (rows slen-1..tm+1), fwd flag from
//                blockIdx -> SGPR-uniform -> scalar branches, zero bloat.
// Chain body verbatim R4: gather-all DPP/permlane tree (probe-validated),
// 32 fdot2 on 8 accumulators, SAME-STEP exponent renorm (exact 2^-(ex+6)),
// chunk-8 W/prefetch. 2048 independent blocks give the scheduler dynamic
// load balancing + 2-wave/SIMD latency interleave of the unmodified body.
// Chains write {h[64], Ci, gold partial} to d_ws (136 floats/batch);
// a tiny second kernel (stream-ordered, no fences needed) combines:
//   logZ2 = c_base + Ci_f + Ci_b + log2(sum_i qf_i qb_i),  one atomicAdd.
// bwd init analytic: qb = E[:,63] (end-obs delta on lane 63) with W row
// slen-1 folded; last bwd step W=1. qb=0 on lanes 62/63 (E rows 62/63 = 0)
// kills fwd junk lanes in the combine. Factorization verified in R6/R7
// (absmax 0.0). Gold split: fwd block t<256, bwd block t>=256.

#define SMALLF   (-1000.0f)
#define LOG2E_F  1.4426950408889634f
#define LN2_F    0.6931471805599453f
#define WS_STRIDE 136                   // floats per batch in d_ws

#if defined(__has_builtin)
#if __has_builtin(__builtin_amdgcn_exp2f)
#define EXP2F(x) __builtin_amdgcn_exp2f(x)
#else
#define EXP2F(x) exp2f(x)
#endif
#if __has_builtin(__builtin_amdgcn_logf)
#define LOG2F(x) __builtin_amdgcn_logf(x)
#else
#define LOG2F(x) log2f(x)
#endif
#else
#define EXP2F(x) exp2f(x)
#define LOG2F(x) log2f(x)
#endif

typedef _Float16 h2 __attribute__((ext_vector_type(2)));

#if defined(__has_builtin) && __has_builtin(__builtin_amdgcn_fdot2)
#define FDOT2(a, b, c) __builtin_amdgcn_fdot2((a), (b), (c), false)
#else
#define FDOT2(a, b, c) fmaf((float)(a).x, (float)(b).x, \
                            fmaf((float)(a).y, (float)(b).y, (c)))
#endif

// DPP move: dst[lane] = src[perm(lane)], full masks, all lanes active.
template <int CTRL>
__device__ __forceinline__ unsigned dppmov(unsigned v) {
    return (unsigned)__builtin_amdgcn_update_dpp((int)v, (int)v, CTRL, 0xF, 0xF, false);
}
#define DPP_QP_X1 0xB1   // quad_perm xor1
#define DPP_QP_X2 0x4E   // quad_perm xor2
#define DPP_ROR4  0x124
#define DPP_ROR8  0x128  // within-16 rotate 8 = xor8 either direction
#define DPP_ROR12 0x12C

// +-4 stage in the 16-row: ror4/ror12 select by lane bit2; the init-time
// probe records the exact resulting row order.
__device__ __forceinline__ unsigned x4sel(unsigned v, bool b2) {
    const unsigned a = dppmov<DPP_ROR4>(v);
    const unsigned b = dppmov<DPP_ROR12>(v);
    return b2 ? a : b;
}

// Half-swap exchanges, BOTH outputs kept; probe tracks orientation.
#define SWAP16(a, b) asm("v_permlane16_swap_b32 %0, %1" : "+v"(a), "+v"(b))
#define SWAP32(a, b) asm("v_permlane32_swap_b32 %0, %1" : "+v"(a), "+v"(b))

__device__ __forceinline__ float bcast_first(float v) {
    return __uint_as_float(__builtin_amdgcn_readfirstlane(__float_as_uint(v)));
}

// SAME-STEP wave-uniform scale 2^-(ex+6) from ss_lane0; accumulates into Ci.
__device__ __forceinline__ float step_scale(float ss, int& Ci) {
    const float s0 = bcast_first(ss);
    const int ex = (int)((__float_as_uint(s0) >> 23) & 0xFF) - 127;  // s0>0 normal
    Ci += ex + 6;
    return __uint_as_float((unsigned)(127 - ex - 6) << 23);          // exact 2^-(ex+6)
}

// ss[lane] = sum over ALL 64 slots i of h_i * Eh[probed slot][lane].
// Gather-all tree: pack(me,x1) -> x2 -> x4sel -> x8 -> swap16(both) ->
// swap32(both) = 32 h2 regs; 32 fdot2 on 8 accumulators; 3-level add tree.
__device__ __forceinline__ float step_ss(float hf,
                                         const h2* __restrict__ Eh,
                                         bool b2) {
    unsigned r[32];
    const unsigned n1 = dppmov<DPP_QP_X1>(__float_as_uint(hf));
    r[0] = __builtin_bit_cast(unsigned,
              __builtin_amdgcn_cvt_pkrtz(hf, __uint_as_float(n1)));
    r[1] = dppmov<DPP_QP_X2>(r[0]);
    r[2] = x4sel(r[0], b2);
    r[3] = x4sel(r[1], b2);
    r[4] = dppmov<DPP_ROR8>(r[0]);
    r[5] = dppmov<DPP_ROR8>(r[1]);
    r[6] = dppmov<DPP_ROR8>(r[2]);
    r[7] = dppmov<DPP_ROR8>(r[3]);
#pragma unroll
    for (int k = 0; k < 8; ++k) { r[8 + k] = r[k]; SWAP16(r[k], r[8 + k]); }
#pragma unroll
    for (int k = 0; k < 16; ++k) { r[16 + k] = r[k]; SWAP32(r[k], r[16 + k]); }
    float a[8];
#pragma unroll
    for (int j = 0; j < 8; ++j) a[j] = 0.f;
#pragma unroll
    for (int k = 0; k < 32; ++k)
        a[k & 7] = FDOT2(__builtin_bit_cast(h2, r[k]), Eh[k], a[k & 7]);
    return ((a[0] + a[1]) + (a[2] + a[3])) + ((a[4] + a[5]) + (a[6] + a[7]));
}

__global__ __launch_bounds__(64, 1) void crf_chain_kernel(
    const float* __restrict__ pred,     // (B,T,L)
    const int*   __restrict__ ref,      // (B,T)
    const int*   __restrict__ seq_len,  // (B,)
    const float* __restrict__ trans,    // (64,64)
    float*       __restrict__ ws,       // (B, WS_STRIDE)
    int T, int L)
{
    const int cid = blockIdx.x;
    const int b   = cid >> 1;
    const bool fwd = (cid & 1) == 0;        // SGPR-uniform
    const unsigned lane = threadIdx.x;
    const int slen = seq_len[b];
    const int nmid = slen - 1;
    const float* prow = pred + (size_t)b * T * L;
    const int*   rrow = ref  + (size_t)b * T;
    const bool mine = (lane < 62);
    const bool b2 = (lane & 4u) != 0;
    float* wsb = ws + (size_t)b * WS_STRIDE;

    // ---- gold score: fwd block t<256 (k=0..3), bwd block t>=256 (k=4..7)
    const int kb = fwd ? 0 : 4;
    int cidx[4], pidx[4];
#pragma unroll
    for (int k = 0; k < 4; ++k) {
        const int t = (int)lane + ((k + kb) << 6);
        cidx[k] = (t < slen) ? rrow[t] : 0;
        pidx[k] = (t >= 1 && t < slen) ? rrow[t - 1] : 0;
    }
    float gacc = 0.f;
#pragma unroll
    for (int k = 0; k < 4; ++k) {
        const int t = (int)lane + ((k + kb) << 6);
        if (t < slen) {
            gacc += prow[(size_t)t * L + cidx[k]];
            if (t >= 1) gacc += trans[(pidx[k] << 6) + cidx[k]];
        }
    }
    if (fwd && lane == 0)
        gacc += trans[(62 << 6) + rrow[0]] + trans[(rrow[slen - 1] << 6) + 63];

    // ---- probe the gather tree (payload = packed lane ids) ---------------
    unsigned gp[32];
    gp[0] = lane | (dppmov<DPP_QP_X1>(lane) << 16);
    gp[1] = dppmov<DPP_QP_X2>(gp[0]);
    gp[2] = x4sel(gp[0], b2);
    gp[3] = x4sel(gp[1], b2);
    gp[4] = dppmov<DPP_ROR8>(gp[0]);
    gp[5] = dppmov<DPP_ROR8>(gp[1]);
    gp[6] = dppmov<DPP_ROR8>(gp[2]);
    gp[7] = dppmov<DPP_ROR8>(gp[3]);
#pragma unroll
    for (int k = 0; k < 8; ++k) { gp[8 + k] = gp[k]; SWAP16(gp[k], gp[8 + k]); }
#pragma unroll
    for (int k = 0; k < 16; ++k) { gp[16 + k] = gp[k]; SWAP32(gp[k], gp[16 + k]); }

    // ---- E fragments in probed order: fwd column-dot, bwd row-dot --------
    h2 Eh[32];
    float psum = 0.f;                       // meaningful for fwd only
#pragma unroll
    for (int k = 0; k < 32; ++k) {
        const unsigned rlo = gp[k] & 0xFFFFu;
        const unsigned rhi = gp[k] >> 16;
        const unsigned iLo = fwd ? (rlo * 64u + lane) : (lane * 64u + rlo);
        const unsigned iHi = fwd ? (rhi * 64u + lane) : (lane * 64u + rhi);
        const float e0 = EXP2F(trans[iLo] * LOG2E_F);
        const float e1 = EXP2F(trans[iHi] * LOG2E_F);
        Eh[k].x = (_Float16)e0; Eh[k].y = (_Float16)e1;
        psum += e0 + e1;                    // rows 62/63 contribute 0 (fwd)
    }

    // ---- chain split (R6/R7-verified): fwd rows 0..tm, bwd slen-1..tm+1 --
    const int fwd_mid = nmid >> 1;
    const int bwd_mid = nmid - fwd_mid;
    const int nsteps  = fwd ? fwd_mid : bwd_mid;

    // ---- init
    int Ci = 0;
    float h;
    if (fwd) {                               // row 0 + psum, exact renorm
        const float q0 = psum * EXP2F((mine ? prow[lane] : 0.f) * LOG2E_F);
        const float sc = step_scale(q0, Ci);
        h = q0 * sc;
    } else {                                 // qb = E[:,63]; fold W row slen-1
        const float Elast = EXP2F(trans[lane * 64u + 63u] * LOG2E_F); // 0 on 62/63
        float Wb0 = 1.0f;
        if (bwd_mid > 0) {
            const float pv = mine ? prow[(size_t)(slen - 1) * L + lane] : 0.f;
            Wb0 = mine ? EXP2F(pv * LOG2E_F) : 0.f;
        }
        h = Elast * Wb0;                     // f16-safe range unrenormed
    }

    // ---- middle steps, chunk 8 (R4 structure); W row for step m:
    //      fwd: m+1; bwd: slen-2-m (last bwd step: W=1)
    float cur[8];
#pragma unroll
    for (int u = 0; u < 8; ++u) {
        int r = fwd ? (u + 1) : (slen - 2 - u);
        r = (r < 0) ? 0 : ((r < T) ? r : (T - 1));
        cur[u] = mine ? prow[(size_t)r * L + lane] : 0.f;
    }

    for (int m0 = 0; m0 < nsteps; m0 += 8) {
        float W[8], nxt[8];
#pragma unroll
        for (int u = 0; u < 8; ++u)          // fwd lanes 62/63: exp(0)=1
            W[u] = (fwd || mine) ? EXP2F(cur[u] * LOG2E_F) : 0.f;
#pragma unroll
        for (int u = 0; u < 8; ++u) {        // prefetch next chunk
            int r = fwd ? (m0 + 9 + u) : (slen - 10 - m0 - u);
            r = (r < 0) ? 0 : ((r < T) ? r : (T - 1));
            nxt[u] = mine ? prow[(size_t)r * L + lane] : 0.f;
        }
#pragma unroll
        for (int u = 0; u < 8; ++u) {
            const int m = m0 + u;
            if (m < nsteps) {                // wave-uniform predicate
                const float ss = step_ss(h, Eh, b2);
                const float sc = step_scale(ss, Ci);
                const float Wu = (!fwd && m == nsteps - 1) ? 1.0f : W[u];
                h = ss * (Wu * sc);
            }
        }
#pragma unroll
        for (int u = 0; u < 8; ++u) cur[u] = nxt[u];
    }

    // ---- in-wave gold reduction; publish chain result --------------------
#pragma unroll
    for (int k = 32; k >= 1; k >>= 1)
        gacc += __shfl_xor(gacc, k, 64);

    wsb[(fwd ? 0 : 64) + lane] = h;
    if (lane == 0) {
        wsb[128 + (fwd ? 0 : 1)] = (float)Ci;   // |Ci| < 2^24: exact
        wsb[130 + (fwd ? 0 : 1)] = gacc;
    }
}

__global__ __launch_bounds__(64, 1) void crf_combine_kernel(
    const float* __restrict__ ws,
    float*       __restrict__ out)
{
    const int b = blockIdx.x;
    const unsigned lane = threadIdx.x;
    const float* wsb = ws + (size_t)b * WS_STRIDE;
    float p = wsb[lane] * wsb[64 + lane];    // qb = 0 on lanes 62/63
#pragma unroll
    for (int k = 32; k >= 1; k >>= 1)
        p += __shfl_xor(p, k, 64);
    if (lane == 0) {
        const float Ci = wsb[128] + wsb[129];
        const float g  = wsb[130] + wsb[131];
        const float logZ2 = SMALLF * LOG2E_F + Ci + LOG2F(p);
        atomicAdd(out, LN2_F * logZ2 - g);
    }
}

extern "C" void kernel_launch(void* const* d_in, const int* in_sizes, int n_in,
                              void* d_out, int out_size, void* d_ws, size_t ws_size,
                              hipStream_t stream) {
    const float* pred  = (const float*)d_in[0];
    const int*   ref   = (const int*)  d_in[1];
    const int*   slen  = (const int*)  d_in[2];
    const float* trans = (const float*)d_in[3];

    const int B = in_sizes[2];                 // 1024
    const int T = in_sizes[1] / B;             // 512
    const int L = in_sizes[0] / in_sizes[1];   // 62

    hipMemsetAsync(d_out, 0, sizeof(float), stream);
    crf_chain_kernel<<<2 * B, 64, 0, stream>>>(pred, ref, slen, trans,
                                               (float*)d_ws, T, L);
    crf_combine_kernel<<<B, 64, 0, stream>>>((const float*)d_ws, (float*)d_out);
}

// Round 9
// 265.718 us; speedup vs baseline: 1.2763x; 1.2691x over previous
//
#include <hip/hip_runtime.h>

// CRF loss (B=1024, T=512, L=62, K=64) for MI355X / gfx950.
// One 64-lane wave per batch (lane j = state j), 1024 blocks -> 1 wave/SIMD:
// runtime = straggler slen x per-step DEPENDENT LATENCY (no TLP exists).
// Linear-domain recursion q_j <- W_j * sum_i q_i E_ij, E = exp(trans).
//
// R9 = R4 structure (full fwd chain, merge-dot body; 118us validated) with
// the per-step renorm chain REMOVED:
//  - constant exact 2^-7 folded into W (exp2(x*log2e - 7), off-chain batch);
//    per-step magnitude ~stationary since column sums ~2^6.7.
//  - exact exponent re-centering (readfirstlane) once per 8-step CHUNK, not
//    per step. Ci bookkeeping: += 7*nmid (constant) + per-chunk ex+6. Exact.
//  - stability: direct feedback at chunk granularity (NOT R5's 2-step-delay
//    resonator). h kept f32; cvt-to-f16 underflow recoverable; fminf top
//    clamp; ex >= -60 guard. Drift/chunk ~ +-4 bits vs +-15 bits headroom.
//  - dot accumulators depth 8 -> 4 (8 accs + 1 extra add level).
// Per-step chain: cvt_pkrtz -> DPP gather-16 -> 32 fdot2 (depth 4) -> adds
// -> permlane merge (probed) -> mul W -> min. No readfirstlane, no SALU.
// Splits (R6/R7/R8: 196/194/174us) all lost to R4's 118us -> reverted.
// First step analytic (uniform SMALL -> c_base); final step in log domain.
// Gold path score fused; one atomicAdd(ln2*logZ2 - gold) per block.

#define SMALLF   (-1000.0f)
#define LOG2E_F  1.4426950408889634f
#define LN2_F    0.6931471805599453f

#if defined(__has_builtin)
#if __has_builtin(__builtin_amdgcn_exp2f)
#define EXP2F(x) __builtin_amdgcn_exp2f(x)
#else
#define EXP2F(x) exp2f(x)
#endif
#if __has_builtin(__builtin_amdgcn_logf)
#define LOG2F(x) __builtin_amdgcn_logf(x)
#else
#define LOG2F(x) log2f(x)
#endif
#else
#define EXP2F(x) exp2f(x)
#define LOG2F(x) log2f(x)
#endif

typedef _Float16 h2 __attribute__((ext_vector_type(2)));

#if defined(__has_builtin) && __has_builtin(__builtin_amdgcn_fdot2)
#define FDOT2(a, b, c) __builtin_amdgcn_fdot2((a), (b), (c), false)
#else
#define FDOT2(a, b, c) fmaf((float)(a).x, (float)(b).x, \
                            fmaf((float)(a).y, (float)(b).y, (c)))
#endif

// DPP move: dst[lane] = src[perm(lane)], full masks, all lanes active.
template <int CTRL>
__device__ __forceinline__ unsigned dppmov(unsigned v) {
    return (unsigned)__builtin_amdgcn_update_dpp((int)v, (int)v, CTRL, 0xF, 0xF, false);
}
#define DPP_QP_X1 0xB1   // quad_perm xor1
#define DPP_QP_X2 0x4E   // quad_perm xor2
#define DPP_ROR4  0x124
#define DPP_ROR8  0x128  // within-16 rotate 8 = xor8 either direction
#define DPP_ROR12 0x12C

// +-4 stage in the 16-row: ror4/ror12 select by lane bit2; the init-time
// probe records the exact resulting row order.
__device__ __forceinline__ unsigned x4sel(unsigned v, bool b2) {
    const unsigned a = dppmov<DPP_ROR4>(v);
    const unsigned b = dppmov<DPP_ROR12>(v);
    return b2 ? a : b;
}

// 16-boundary exchange: both operands preloaded with v; outputs are the two
// group-patterns; per-lane select (parity ^ probed flip) = lane <-> lane^16.
__device__ __forceinline__ unsigned x16(unsigned v, bool sel) {
    unsigned a = v, b = v;
    asm("v_permlane16_swap_b32 %0, %1" : "+v"(a), "+v"(b));
    return sel ? a : b;
}
// 32-boundary exchange, same construction.
__device__ __forceinline__ unsigned x32(unsigned v, bool sel) {
    unsigned a = v, b = v;
    asm("v_permlane32_swap_b32 %0, %1" : "+v"(a), "+v"(b));
    return sel ? a : b;
}

__device__ __forceinline__ float bcast_first(float v) {
    return __uint_as_float(__builtin_amdgcn_readfirstlane(__float_as_uint(v)));
}

// wave-uniform exact scale 2^-(ex+6) from s_lane0; accumulates ex+6 into Ci.
// Used at INIT and once per CHUNK only (off the per-step chain).
__device__ __forceinline__ float step_scale(float ss, int& Ci) {
    const float s0 = bcast_first(ss);
    int ex = (int)((__float_as_uint(s0) >> 23) & 0xFF) - 127;
    ex = (ex < -60) ? -60 : ex;                                  // 0-guard
    Ci += ex + 6;
    return __uint_as_float((unsigned)(127 - ex - 6) << 23);      // exact 2^-(ex+6)
}

// One recursion dot: per-lane h (f32) -> ss[lane] = sum_i h_i E[i][lane].
// Gather-16 DPP tree, 4 column-partials on 8 accumulators (depth 4),
// permlane merges (probed). R4-validated network; only acc split changed.
__device__ __forceinline__ float step_ss(float hf,
                                         const h2* __restrict__ EhA,
                                         const h2* __restrict__ EhB,
                                         const h2* __restrict__ EhC,
                                         const h2* __restrict__ EhD,
                                         bool b2, bool s16, bool s32) {
    const unsigned n1 = dppmov<DPP_QP_X1>(__float_as_uint(hf));
    unsigned r[8];
    r[0] = __builtin_bit_cast(unsigned,
              __builtin_amdgcn_cvt_pkrtz(hf, __uint_as_float(n1)));
    r[1] = dppmov<DPP_QP_X2>(r[0]);
    r[2] = x4sel(r[0], b2);
    r[3] = x4sel(r[1], b2);
    r[4] = dppmov<DPP_ROR8>(r[0]);
    r[5] = dppmov<DPP_ROR8>(r[1]);
    r[6] = dppmov<DPP_ROR8>(r[2]);
    r[7] = dppmov<DPP_ROR8>(r[3]);
    float a0 = 0.f, a1 = 0.f, a2 = 0.f, a3 = 0.f;
    float a4 = 0.f, a5 = 0.f, a6 = 0.f, a7 = 0.f;
#pragma unroll
    for (int k = 0; k < 4; ++k) {
        const h2 v = __builtin_bit_cast(h2, r[k]);
        a0 = FDOT2(v, EhA[k], a0);
        a1 = FDOT2(v, EhB[k], a1);
        a2 = FDOT2(v, EhC[k], a2);
        a3 = FDOT2(v, EhD[k], a3);
    }
#pragma unroll
    for (int k = 4; k < 8; ++k) {
        const h2 v = __builtin_bit_cast(h2, r[k]);
        a4 = FDOT2(v, EhA[k], a4);
        a5 = FDOT2(v, EhB[k], a5);
        a6 = FDOT2(v, EhC[k], a6);
        a7 = FDOT2(v, EhD[k], a7);
    }
    const float pA = a0 + a4, pB = a1 + a5, pC = a2 + a6, pD = a3 + a7;
    const float A  = pA + __uint_as_float(x16(__float_as_uint(pB), s16));
    const float A2 = pC + __uint_as_float(x16(__float_as_uint(pD), s16));
    return A + __uint_as_float(x32(__float_as_uint(A2), s32));
}

__global__ __launch_bounds__(64, 1) void crf_fused_kernel(
    const float* __restrict__ pred,     // (B,T,L)
    const int*   __restrict__ ref,      // (B,T)
    const int*   __restrict__ seq_len,  // (B,)
    const float* __restrict__ trans,    // (64,64)
    float*       __restrict__ out,      // scalar, pre-zeroed
    int T, int L)
{
    const int b    = blockIdx.x;
    const unsigned lane = threadIdx.x;
    const int slen = seq_len[b];
    const int nmid = slen - 1;              // middle steps t = 2..slen
    const float* prow = pred + (size_t)b * T * L;
    const int*   rrow = ref  + (size_t)b * T;
    const bool mine = (lane < 62);
    const bool b2 = (lane & 4u) != 0;

    // ---- gold score, two-phase gather (indices first, then values)
    int cidx[8], pidx[8];
#pragma unroll
    for (int k = 0; k < 8; ++k) {
        const int t = (int)lane + (k << 6);
        cidx[k] = (t < slen) ? rrow[t] : 0;
        pidx[k] = (t >= 1 && t < slen) ? rrow[t - 1] : 0;
    }
    float gacc = 0.f;
#pragma unroll
    for (int k = 0; k < 8; ++k) {
        const int t = (int)lane + (k << 6);
        if (t < slen) {
            gacc += prow[(size_t)t * L + cidx[k]];
            if (t >= 1) gacc += trans[(pidx[k] << 6) + cidx[k]];
        }
    }
    if (lane == 0)
        gacc += trans[(62 << 6) + rrow[0]] + trans[(rrow[slen - 1] << 6) + 63];

    // ---- probe the exchange network (payload = lane id) ------------------
    bool flip16 = false, flip32 = false;
    {
        const unsigned p = x16(lane, ((lane >> 4) & 1u) != 0);
        if (__builtin_amdgcn_readfirstlane((int)p) == 0) flip16 = true;
        const unsigned q = x32(lane, ((lane >> 5) & 1u) != 0);
        if (__builtin_amdgcn_readfirstlane((int)q) == 0) flip32 = true;
    }
    const bool s16 = ((((lane >> 4) & 1u) != 0) != flip16);
    const bool s32 = ((((lane >> 5) & 1u) != 0) != flip32);
    const unsigned m16 = x16(lane, s16);        // my 16-exchange partner
    const unsigned m32 = x32(lane, s32);        // my 32-exchange partner
    const unsigned cD  = x16(m32, s16);         // = 32-partner of my 16-partner

    // probe the gather: packed two lane-ids per reg, same ops as step_ss
    unsigned gp[8];
    gp[0] = lane | (dppmov<DPP_QP_X1>(lane) << 16);
    gp[1] = dppmov<DPP_QP_X2>(gp[0]);
    gp[2] = x4sel(gp[0], b2);
    gp[3] = x4sel(gp[1], b2);
    gp[4] = dppmov<DPP_ROR8>(gp[0]);
    gp[5] = dppmov<DPP_ROR8>(gp[1]);
    gp[6] = dppmov<DPP_ROR8>(gp[2]);
    gp[7] = dppmov<DPP_ROR8>(gp[3]);

    // ---- E fragments per probed row order, 4 column sets -----------------
    h2 EhA[8], EhB[8], EhC[8], EhD[8];
    float sA = 0.f, sB = 0.f, sC = 0.f, sD = 0.f;   // partial col-sums for psum
#pragma unroll
    for (int k = 0; k < 8; ++k) {
        const unsigned rlo = gp[k] & 0xFFFFu;
        const unsigned rhi = gp[k] >> 16;
        const float a0 = EXP2F(trans[rlo * 64u + lane] * LOG2E_F);
        const float a1 = EXP2F(trans[rhi * 64u + lane] * LOG2E_F);
        EhA[k].x = (_Float16)a0; EhA[k].y = (_Float16)a1; sA += a0 + a1;
        const float b0 = EXP2F(trans[rlo * 64u + m16] * LOG2E_F);
        const float b1 = EXP2F(trans[rhi * 64u + m16] * LOG2E_F);
        EhB[k].x = (_Float16)b0; EhB[k].y = (_Float16)b1; sB += b0 + b1;
        const float c0 = EXP2F(trans[rlo * 64u + m32] * LOG2E_F);
        const float c1 = EXP2F(trans[rhi * 64u + m32] * LOG2E_F);
        EhC[k].x = (_Float16)c0; EhC[k].y = (_Float16)c1; sC += c0 + c1;
        const float d0 = EXP2F(trans[rlo * 64u + cD] * LOG2E_F);
        const float d1 = EXP2F(trans[rhi * 64u + cD] * LOG2E_F);
        EhD[k].x = (_Float16)d0; EhD[k].y = (_Float16)d1; sD += d0 + d1;
    }
    // psum_j = sum_i E[i][j] via the same merge network (h == 1 self-check)
    const float psA  = sA + __uint_as_float(x16(__float_as_uint(sB), s16));
    const float psA2 = sC + __uint_as_float(x16(__float_as_uint(sD), s16));
    const float psum = psA + __uint_as_float(x32(__float_as_uint(psA2), s32));

    // ---- preload obs rows 1..8 (row for step m is m+1, clamped)
    float cur[8];
#pragma unroll
    for (int u = 0; u < 8; ++u) {
        const int row = (u + 1 < T) ? (u + 1) : (T - 1);
        cur[u] = mine ? prow[(size_t)row * L + lane] : 0.f;
    }

    // ---- init (t=1): q = exp2(pred0) * psum; uniform SMALL -> c_base
    int Ci = 0;                              // integer scale accumulator
    const float c_base = SMALLF * LOG2E_F;
    float hf;
    {
        const float q0 = psum * EXP2F((mine ? prow[lane] : 0.f) * LOG2E_F);
        const float sc = step_scale(q0, Ci);
        hf = q0 * sc;
    }

    // ---- middle steps m = 0..nmid-1 in chunks of 8 (step m uses row m+1).
    // W carries the constant 2^-7 (exp2 arg -7); renorm once per chunk.
    const int nfull = nmid >> 3;
    const int rem   = nmid & 7;
    for (int c = 0; c < nfull; ++c) {
        float W[8], nxt[8];
#pragma unroll
        for (int u = 0; u < 8; ++u)
            W[u] = EXP2F(cur[u] * LOG2E_F - 7.0f);   // off-chain, pre-scaled
        const int base = 8 * (c + 1) + 1;
#pragma unroll
        for (int u = 0; u < 8; ++u) {                // issue next chunk's loads
            const int row = (base + u < T) ? (base + u) : (T - 1);
            nxt[u] = mine ? prow[(size_t)row * L + lane] : 0.f;
        }
#pragma unroll
        for (int u = 0; u < 8; ++u) {
            const float ss = step_ss(hf, EhA, EhB, EhC, EhD, b2, s16, s32);
            hf = fminf(ss * W[u], 60000.f);          // chain: dot -> mul -> min
        }
        const float sc = step_scale(hf, Ci);         // once per chunk
        hf *= sc;
#pragma unroll
        for (int u = 0; u < 8; ++u) cur[u] = nxt[u];
    }

    // ---- remainder middle steps: cur[u] holds row 8*nfull+1+u
    float Wr[7];
#pragma unroll
    for (int u = 0; u < 7; ++u)
        Wr[u] = EXP2F(cur[u] * LOG2E_F - 7.0f);
#pragma unroll
    for (int u = 0; u < 7; ++u) {
        if (u < rem) {
            const float ss = step_ss(hf, EhA, EhB, EhC, EhD, b2, s16, s32);
            hf = fminf(ss * Wr[u], 60000.f);
        }
    }
    Ci += 7 * nmid;                          // constant 2^-7 per middle step

    // ---- final step t = slen+1 in log domain (e_s has +1000)
    {
        const float ssf = step_ss(hf, EhA, EhB, EhC, EhD, b2, s16, s32);
        const float pvf = (slen < T) ? cur[rem] : 0.f;  // pred row slen (or r_pad)
        float ob;
        if (lane < 62)       ob = pvf + SMALLF;  // pred/r_pad + e_s SMALL
        else if (lane == 62) ob = SMALLF;        // SMALL + 0
        else                 ob = 0.f;           // SMALL + 1000
        const float alpha = c_base + (float)Ci + LOG2F(ssf) + ob * LOG2E_F;

        float mx = alpha;
#pragma unroll
        for (int k = 32; k >= 1; k >>= 1)
            mx = fmaxf(mx, __shfl_xor(mx, k, 64));
        float pe = EXP2F(alpha - mx);
#pragma unroll
        for (int k = 32; k >= 1; k >>= 1)
            pe += __shfl_xor(pe, k, 64);
#pragma unroll
        for (int k = 32; k >= 1; k >>= 1)
            gacc += __shfl_xor(gacc, k, 64);

        if (lane == 0) {
            const float logZ2 = mx + LOG2F(pe);  // base-2
            atomicAdd(out, LN2_F * logZ2 - gacc);
        }
    }
}

extern "C" void kernel_launch(void* const* d_in, const int* in_sizes, int n_in,
                              void* d_out, int out_size, void* d_ws, size_t ws_size,
                              hipStream_t stream) {
    const float* pred  = (const float*)d_in[0];
    const int*   ref   = (const int*)  d_in[1];
    const int*   slen  = (const int*)  d_in[2];
    const float* trans = (const float*)d_in[3];

    const int B = in_sizes[2];                 // 1024
    const int T = in_sizes[1] / B;             // 512
    const int L = in_sizes[0] / in_sizes[1];   // 62

    hipMemsetAsync(d_out, 0, sizeof(float), stream);
    crf_fused_kernel<<<B, 64, 0, stream>>>(pred, ref, slen, trans,
                                           (float*)d_out, T, L);
}